// Round 12
// baseline (330.439 us; speedup 1.0000x reference)
//
#include <hip/hip_runtime.h>
#include <hip/hip_cooperative_groups.h>
#include <math.h>

namespace cg = cooperative_groups;

// ---------------------------------------------------------------------------
// Pipeline v8 — bucket pass + ONE persistent cooperative kernel.
// r7-r11 finding: any kernel that makes a global pass over the 8M-edge file
// costs ~45-55us regardless of per-edge work (atomics / scalar walk / seg-
// scan). So minimize global edge passes: fuse sort+agg1+agg2 into one
// cooperative kernel where block b sorts bucket b in LDS and KEEPS it there
// across grid.sync()s. Sorted-file write-back (32MB) and both re-reads
// (64MB) vanish; agg loops' only global op is the u/q gather.
//   k_bucket : radix pass 1 (dst>>10), one LDS atomic/edge (rank-first),
//              shuffle scan, coalesced per-wave run write-out.
//   k_fused  : [A] per-bucket sort by dstlo in LDS (rank atomic == degree
//              histogram), dinv kept in registers, u=bf16(x*dinv) to global
//              -> grid.sync()
//              [B] per-node LDS segment walk, gather u, MLP 1->16->2,
//              q packed 2xbf16 to global; self-values stay in registers
//              -> grid.sync()
//              [C] same walk, gather q, +self, *dinv, +b2, log_softmax.
// Fallback (deterministic): r11 separate kernels if cooperative can't fit.
// ---------------------------------------------------------------------------

#define NPB 1024            // nodes per bucket
#define NPB_SHIFT 10
#define NPB_MASK (NPB - 1)
#define MAXB 512            // max buckets (also co-residency cap: 2/CU * 256)
#define P1T 512             // k_bucket threads
#define CHUNK 16384         // edges per k_bucket block
#define EPT 32              // CHUNK / P1T edges per thread
#define SORT_CAP 17408      // per-bucket file capacity
#define SPT 17              // SORT_CAP / 1024 entries per sort thread

__device__ __forceinline__ unsigned short f2bf(float f) {
    unsigned int x = __float_as_uint(f);
    x += 0x7fffu + ((x >> 16) & 1u);            // round-to-nearest-even
    return (unsigned short)(x >> 16);
}
__device__ __forceinline__ float bf2f(unsigned short h) {
    return __uint_as_float((unsigned int)h << 16);
}

// ---------------------------------------------------------------------------
// Phase 1: bucket by dst>>10. One LDS atomic per edge (rank-first).
// ---------------------------------------------------------------------------
__global__ __launch_bounds__(P1T) void k_bucket(
    const int* __restrict__ src, const int* __restrict__ dst,
    unsigned int* __restrict__ file, int* __restrict__ ctr,
    int E, int nbucket, int cap)
{
    __shared__ unsigned int sorted[CHUNK];   // 64 KB
    __shared__ int rk[MAXB];
    __shared__ int pre[MAXB + 1];
    __shared__ int gb[MAXB];
    __shared__ int wsum[P1T / 64];

    const int t  = threadIdx.x;
    const int e0 = blockIdx.x * CHUNK;
    const int nE = min(CHUNK, E - e0);

    for (int b = t; b < MAXB; b += P1T) rk[b] = 0;
    __syncthreads();

    const bool full = (nE == CHUNK);
    int4 dc[8];
    int  rnk[EPT];

    if (full) {
        const int4* d4 = (const int4*)(dst + e0);
#pragma unroll
        for (int k = 0; k < 8; ++k) dc[k] = d4[t + k * P1T];
#pragma unroll
        for (int k = 0; k < 8; ++k) {
            rnk[4 * k]     = atomicAdd(&rk[((unsigned)dc[k].x) >> NPB_SHIFT], 1);
            rnk[4 * k + 1] = atomicAdd(&rk[((unsigned)dc[k].y) >> NPB_SHIFT], 1);
            rnk[4 * k + 2] = atomicAdd(&rk[((unsigned)dc[k].z) >> NPB_SHIFT], 1);
            rnk[4 * k + 3] = atomicAdd(&rk[((unsigned)dc[k].w) >> NPB_SHIFT], 1);
        }
    } else {
        int k = 0;
        for (int i = t; i < nE; i += P1T, ++k)
            rnk[k] = atomicAdd(&rk[((unsigned)dst[e0 + i]) >> NPB_SHIFT], 1);
    }
    __syncthreads();

    {
        const int lane = t & 63, wv = t >> 6;
        int v = (t < nbucket) ? rk[t] : 0;
#pragma unroll
        for (int d = 1; d < 64; d <<= 1) {
            int nv = __shfl_up(v, d, 64);
            if (lane >= d) v += nv;
        }
        if (lane == 63) wsum[wv] = v;
        __syncthreads();
        if (t < P1T / 64) {
            int s = wsum[t];
#pragma unroll
            for (int d = 1; d < P1T / 64; d <<= 1) {
                int ns = __shfl_up(s, d, P1T / 64);
                if (t >= d) s += ns;
            }
            wsum[t] = s;
        }
        __syncthreads();
        pre[t + 1] = (wv ? wsum[wv - 1] : 0) + v;
        if (t == 0) pre[0] = 0;
    }
    __syncthreads();

    for (int b = t; b < nbucket; b += P1T) {
        int c = pre[b + 1] - pre[b];
        gb[b] = c ? atomicAdd(&ctr[b], c) : 0;
    }
    __syncthreads();

    if (full) {
        const int4* s4 = (const int4*)(src + e0);
#pragma unroll
        for (int k = 0; k < 8; ++k) {
            int4 s = s4[t + k * P1T];
            int4 d = dc[k];
            sorted[pre[((unsigned)d.x) >> NPB_SHIFT] + rnk[4 * k]] =
                (((unsigned)s.x) << NPB_SHIFT) | ((unsigned)d.x & NPB_MASK);
            sorted[pre[((unsigned)d.y) >> NPB_SHIFT] + rnk[4 * k + 1]] =
                (((unsigned)s.y) << NPB_SHIFT) | ((unsigned)d.y & NPB_MASK);
            sorted[pre[((unsigned)d.z) >> NPB_SHIFT] + rnk[4 * k + 2]] =
                (((unsigned)s.z) << NPB_SHIFT) | ((unsigned)d.z & NPB_MASK);
            sorted[pre[((unsigned)d.w) >> NPB_SHIFT] + rnk[4 * k + 3]] =
                (((unsigned)s.w) << NPB_SHIFT) | ((unsigned)d.w & NPB_MASK);
        }
    } else {
        int k = 0;
        for (int i = t; i < nE; i += P1T, ++k) {
            int d = dst[e0 + i];
            int b = ((unsigned)d) >> NPB_SHIFT;
            sorted[pre[b] + rnk[k]] =
                (((unsigned)src[e0 + i]) << NPB_SHIFT) | ((unsigned)d & NPB_MASK);
        }
    }
    __syncthreads();

    {
        const int wid  = t >> 6;
        const int lane = t & 63;
        const int nw   = P1T >> 6;
        for (int b = wid; b < nbucket; b += nw) {
            int s0 = pre[b], s1 = pre[b + 1];
            int base = gb[b];
            unsigned int* dp = file + (size_t)b * cap;
            for (int j = s0 + lane; j < s1; j += 64) {
                int idx = base + (j - s0);
                if (idx < cap)
                    __builtin_nontemporal_store(sorted[j], &dp[idx]);
            }
        }
    }
}

// ---------------------------------------------------------------------------
// Fused cooperative kernel: sort (LDS-resident) + agg1 + agg2.
// ---------------------------------------------------------------------------
__global__ __launch_bounds__(NPB, 8) void k_fused(
    const unsigned int* __restrict__ file, const int* __restrict__ ctr,
    const float* __restrict__ x, unsigned short* __restrict__ u,
    unsigned int* __restrict__ q, const float* __restrict__ W1,
    const float* __restrict__ b1, const float* __restrict__ W2,
    const float* __restrict__ b2, float2* __restrict__ out,
    int N, int cap)
{
    __shared__ unsigned int sorted[SORT_CAP];  // 69.6 KB, lives all phases
    __shared__ int cnt[NPB];
    __shared__ int pre[NPB + 1];
    __shared__ int wsum[NPB / 64];

    const int t = threadIdx.x;
    const int b = blockIdx.x;
    const int nb = min(ctr[b], cap);
    const unsigned int* f = file + (size_t)b * cap;
    const int g = b * NPB + t;

    cg::grid_group grid = cg::this_grid();

    // ===== Phase A: sort bucket by dstlo; deg -> dinv; u = bf16(x*dinv) ====
    cnt[t] = 0;
    __syncthreads();

    unsigned int ev[SPT];
    int rk_[SPT];
#pragma unroll
    for (int k = 0; k < SPT; ++k) {
        int i = t + (k << NPB_SHIFT);
        if (i < nb) ev[k] = __builtin_nontemporal_load(f + i);
    }
#pragma unroll
    for (int k = 0; k < SPT; ++k) {
        int i = t + (k << NPB_SHIFT);
        if (i < nb) rk_[k] = atomicAdd(&cnt[ev[k] & NPB_MASK], 1);
    }
    __syncthreads();

    {   // hierarchical inclusive scan of cnt -> pre
        const int lane = t & 63, wv = t >> 6;
        int v = cnt[t];
#pragma unroll
        for (int d = 1; d < 64; d <<= 1) {
            int nv = __shfl_up(v, d, 64);
            if (lane >= d) v += nv;
        }
        if (lane == 63) wsum[wv] = v;
        __syncthreads();
        if (t < NPB / 64) {
            int s = wsum[t];
#pragma unroll
            for (int d = 1; d < NPB / 64; d <<= 1) {
                int ns = __shfl_up(s, d, NPB / 64);
                if (t >= d) s += ns;
            }
            wsum[t] = s;
        }
        __syncthreads();
        pre[t + 1] = (wv ? wsum[wv - 1] : 0) + v;
        if (t == 0) pre[0] = 0;
    }
    __syncthreads();

#pragma unroll
    for (int k = 0; k < SPT; ++k) {
        int i = t + (k << NPB_SHIFT);
        if (i < nb)
            sorted[pre[ev[k] & NPB_MASK] + rk_[k]] = ev[k];
    }

    float dv = 0.f, uself = 0.f;
    if (g < N) {
        dv = rsqrtf((float)(cnt[t] + 1));   // +1 self-loop
        uself = x[g] * dv;
        u[g] = f2bf(uself);
    }
    // sorted[] + pre[] stay in LDS; dv/uself stay in registers.
    grid.sync();

    // ===== Phase B: agg1 = sum u[src] over own segment; MLP; q ============
    float q0self = 0.f, q1self = 0.f;
    {
        int e0 = pre[t], e1 = pre[t + 1];
        float acc = 0.f;
        for (int j = e0; j < e1; ++j)
            acc += bf2f(u[sorted[j] >> NPB_SHIFT]);
        if (g < N) {
            float s1v = (acc + uself) * dv;
            float c0 = 0.f, c1 = 0.f;
#pragma unroll
            for (int k = 0; k < 16; ++k) {
                float h = fmaxf(fmaf(s1v, W1[k], b1[k]), 0.f);
                c0 = fmaf(h, W2[2 * k], c0);
                c1 = fmaf(h, W2[2 * k + 1], c1);
            }
            q0self = c0 * dv;
            q1self = c1 * dv;
            q[g] = (unsigned int)f2bf(q0self) |
                   ((unsigned int)f2bf(q1self) << 16);
        }
    }
    grid.sync();

    // ===== Phase C: agg2 = sum q[src]; log_softmax =========================
    {
        int e0 = pre[t], e1 = pre[t + 1];
        float a0 = 0.f, a1 = 0.f;
        for (int j = e0; j < e1; ++j) {
            unsigned int gq = q[sorted[j] >> NPB_SHIFT];
            a0 += bf2f((unsigned short)gq);
            a1 += bf2f((unsigned short)(gq >> 16));
        }
        if (g < N) {
            float o0 = (a0 + q0self) * dv + b2[0];
            float o1 = (a1 + q1self) * dv + b2[1];
            float m = fmaxf(o0, o1);
            float l = m + logf(expf(o0 - m) + expf(o1 - m));
            out[g] = make_float2(o0 - l, o1 - l);
        }
    }
}

// ===========================================================================
// Non-cooperative fallback tail (r11 structure): sort w/ write-back + aggs.
// ===========================================================================
__global__ __launch_bounds__(NPB) void k_sort(
    unsigned int* __restrict__ file, const int* __restrict__ ctr,
    const float* __restrict__ x, float* __restrict__ dinv,
    unsigned short* __restrict__ u, int N, int cap)
{
    __shared__ unsigned int sorted[SORT_CAP];
    __shared__ int cnt[NPB];
    __shared__ int pre[NPB + 1];
    __shared__ int wsum[NPB / 64];

    const int t = threadIdx.x;
    const int b = blockIdx.x;
    const int nb = min(ctr[b], cap);
    unsigned int* f = file + (size_t)b * cap;

    cnt[t] = 0;
    __syncthreads();

    unsigned int ev[SPT];
    int rk_[SPT];
#pragma unroll
    for (int k = 0; k < SPT; ++k) {
        int i = t + (k << NPB_SHIFT);
        if (i < nb) ev[k] = __builtin_nontemporal_load(f + i);
    }
#pragma unroll
    for (int k = 0; k < SPT; ++k) {
        int i = t + (k << NPB_SHIFT);
        if (i < nb) rk_[k] = atomicAdd(&cnt[ev[k] & NPB_MASK], 1);
    }
    __syncthreads();

    {
        const int lane = t & 63, wv = t >> 6;
        int v = cnt[t];
#pragma unroll
        for (int d = 1; d < 64; d <<= 1) {
            int nv = __shfl_up(v, d, 64);
            if (lane >= d) v += nv;
        }
        if (lane == 63) wsum[wv] = v;
        __syncthreads();
        if (t < NPB / 64) {
            int s = wsum[t];
#pragma unroll
            for (int d = 1; d < NPB / 64; d <<= 1) {
                int ns = __shfl_up(s, d, NPB / 64);
                if (t >= d) s += ns;
            }
            wsum[t] = s;
        }
        __syncthreads();
        pre[t + 1] = (wv ? wsum[wv - 1] : 0) + v;
        if (t == 0) pre[0] = 0;
    }
    __syncthreads();

#pragma unroll
    for (int k = 0; k < SPT; ++k) {
        int i = t + (k << NPB_SHIFT);
        if (i < nb)
            sorted[pre[ev[k] & NPB_MASK] + rk_[k]] = ev[k];
    }
    __syncthreads();

    for (int i = t; i < nb; i += NPB)
        __builtin_nontemporal_store(sorted[i], &f[i]);

    const int g = b * NPB + t;
    if (g < N) {
        float dvv = rsqrtf((float)(cnt[t] + 1));
        dinv[g] = dvv;
        u[g] = f2bf(x[g] * dvv);
    }
}

__global__ __launch_bounds__(256) void k_agg1(
    const unsigned int* __restrict__ file, const int* __restrict__ ctr,
    const unsigned short* __restrict__ u, const float* __restrict__ dinv,
    const float* __restrict__ W1, const float* __restrict__ b1,
    const float* __restrict__ W2, unsigned int* __restrict__ q,
    int N, int cap)
{
    // NOTE: fallback uses per-bucket linear scan via sorted file + local CSR
    // reconstruction from entry keys (scalar walk on matching keys).
    int g = blockIdx.x * 256 + threadIdx.x;
    if (g >= N) return;
    int b = g >> NPB_SHIFT, loc = g & NPB_MASK;
    const unsigned int* f = file + (size_t)b * cap;
    int nb = min(ctr[b], cap);
    float acc = 0.f;
    // binary search first entry with key >= loc (entries sorted by key)
    int lo = 0, hi = nb;
    while (lo < hi) {
        int mid = (lo + hi) >> 1;
        if ((int)(f[mid] & NPB_MASK) < loc) lo = mid + 1; else hi = mid;
    }
    for (int j = lo; j < nb; ++j) {
        unsigned int w = f[j];
        if ((int)(w & NPB_MASK) != loc) break;
        acc += bf2f(u[w >> NPB_SHIFT]);
    }
    float dvv = dinv[g];
    float s1v = (acc + bf2f(u[g])) * dvv;
    float c0 = 0.f, c1 = 0.f;
#pragma unroll
    for (int k = 0; k < 16; ++k) {
        float h = fmaxf(fmaf(s1v, W1[k], b1[k]), 0.f);
        c0 = fmaf(h, W2[2 * k], c0);
        c1 = fmaf(h, W2[2 * k + 1], c1);
    }
    q[g] = (unsigned int)f2bf(c0 * dvv) | ((unsigned int)f2bf(c1 * dvv) << 16);
}

__global__ __launch_bounds__(256) void k_agg2(
    const unsigned int* __restrict__ file, const int* __restrict__ ctr,
    const unsigned int* __restrict__ q, const float* __restrict__ dinv,
    const float* __restrict__ b2, float2* __restrict__ out,
    int N, int cap)
{
    int g = blockIdx.x * 256 + threadIdx.x;
    if (g >= N) return;
    int b = g >> NPB_SHIFT, loc = g & NPB_MASK;
    const unsigned int* f = file + (size_t)b * cap;
    int nb = min(ctr[b], cap);
    float a0 = 0.f, a1 = 0.f;
    int lo = 0, hi = nb;
    while (lo < hi) {
        int mid = (lo + hi) >> 1;
        if ((int)(f[mid] & NPB_MASK) < loc) lo = mid + 1; else hi = mid;
    }
    for (int j = lo; j < nb; ++j) {
        unsigned int w = f[j];
        if ((int)(w & NPB_MASK) != loc) break;
        unsigned int gq = q[w >> NPB_SHIFT];
        a0 += bf2f((unsigned short)gq);
        a1 += bf2f((unsigned short)(gq >> 16));
    }
    float dvv = dinv[g];
    unsigned int qi = q[g];
    float o0 = (a0 + bf2f((unsigned short)qi)) * dvv + b2[0];
    float o1 = (a1 + bf2f((unsigned short)(qi >> 16))) * dvv + b2[1];
    float m = fmaxf(o0, o1);
    float l = m + logf(expf(o0 - m) + expf(o1 - m));
    out[g] = make_float2(o0 - l, o1 - l);
}

// ===========================================================================
extern "C" void kernel_launch(void* const* d_in, const int* in_sizes, int n_in,
                              void* d_out, int out_size, void* d_ws, size_t ws_size,
                              hipStream_t stream) {
    const float* x  = (const float*)d_in[0];
    const int* ei   = (const int*)d_in[1];
    const float* W1 = (const float*)d_in[2];
    const float* b1 = (const float*)d_in[3];
    const float* W2 = (const float*)d_in[4];
    const float* b2 = (const float*)d_in[5];

    const int N = in_sizes[0];
    const int E = in_sizes[1] / 2;
    const int* src = ei;
    const int* dst = ei + E;

    const int nbucket = (N + NPB - 1) / NPB;
    const int cap = ((E / nbucket + 1024) + 63) & ~63;

    auto align_up = [](size_t v) { return (v + 255) & ~(size_t)255; };
    size_t off_ctr   = 0;
    size_t off_file  = align_up((size_t)MAXB * sizeof(int));
    size_t off_dinv  = align_up(off_file + (size_t)nbucket * SORT_CAP * sizeof(unsigned int));
    size_t off_u     = align_up(off_dinv + (size_t)N * sizeof(float));
    size_t off_q     = align_up(off_u + (size_t)N * sizeof(unsigned short));
    size_t needed    = off_q + (size_t)N * sizeof(unsigned int);

    char* ws = (char*)d_ws;

    int*            ctr   = (int*)(ws + off_ctr);
    unsigned int*   file  = (unsigned int*)(ws + off_file);
    float*          dinv  = (float*)(ws + off_dinv);
    unsigned short* u     = (unsigned short*)(ws + off_u);
    unsigned int*   q     = (unsigned int*)(ws + off_q);
    float2*         outp  = (float2*)d_out;

    if (nbucket <= MAXB && cap <= SORT_CAP && needed <= ws_size) {
        (void)hipMemsetAsync(ctr, 0, (size_t)MAXB * sizeof(int), stream);

        const int p1Blocks = (E + CHUNK - 1) / CHUNK;
        k_bucket<<<p1Blocks, P1T, 0, stream>>>(src, dst, file, ctr, E, nbucket, SORT_CAP);

        int capv = SORT_CAP, Nv = N;
        void* args[] = {(void*)&file, (void*)&ctr, (void*)&x, (void*)&u,
                        (void*)&q, (void*)&W1, (void*)&b1, (void*)&W2,
                        (void*)&b2, (void*)&outp, (void*)&Nv, (void*)&capv};
        hipError_t err = hipLaunchCooperativeKernel(
            (const void*)k_fused, dim3(nbucket), dim3(NPB), args, 0, stream);

        if (err != hipSuccess) {
            // deterministic fallback: r11-style separate kernels
            const int nodBlocks = (N + 255) / 256;
            k_sort<<<nbucket, NPB, 0, stream>>>(file, ctr, x, dinv, u, N, SORT_CAP);
            k_agg1<<<nodBlocks, 256, 0, stream>>>(file, ctr, u, dinv, W1, b1, W2, q, N, SORT_CAP);
            k_agg2<<<nodBlocks, 256, 0, stream>>>(file, ctr, q, dinv, b2, outp, N, SORT_CAP);
        }
    } else {
        // shape fallback: bucket + separate kernels (no cooperative need)
        (void)hipMemsetAsync(ctr, 0, (size_t)MAXB * sizeof(int), stream);
        const int p1Blocks = (E + CHUNK - 1) / CHUNK;
        const int nodBlocks = (N + 255) / 256;
        k_bucket<<<p1Blocks, P1T, 0, stream>>>(src, dst, file, ctr, E, nbucket, SORT_CAP);
        k_sort<<<nbucket, NPB, 0, stream>>>(file, ctr, x, dinv, u, N, SORT_CAP);
        k_agg1<<<nodBlocks, 256, 0, stream>>>(file, ctr, u, dinv, W1, b1, W2, q, N, SORT_CAP);
        k_agg2<<<nodBlocks, 256, 0, stream>>>(file, ctr, q, dinv, b2, outp, N, SORT_CAP);
    }
}